// Round 2
// baseline (680.132 us; speedup 1.0000x reference)
//
#include <hip/hip_runtime.h>
#include <math.h>

// GASLayer: per-column EMA normalization with chunked parallel scan.
// T=32768 rows, D=1024 cols. C=512 chunks of L=64 rows.
// Each K1/K3 thread owns 4 consecutive columns (float4 lanes).
// ws layout (floats, n = C*D = 524288 each):
//   [0] sum, [1] sumsq, [2] B_mu, [3] Q0, [4] Q1, [5] mu_in, [6] var_in
// (Q2 is data-independent -> host constant.)
// Total ws use: 7 * 524288 * 4 B = 14 MiB.

#define T_DIM 32768
#define D_DIM 1024
#define CHUNK 512
#define CLEN  (T_DIM / CHUNK)   // 64
#define ETA_MU_F 0.01f
#define ETA_VAR_F 0.02f

typedef float vf4 __attribute__((ext_vector_type(4)));

// K1: one block per chunk; thread j handles columns 4j..4j+3.
// mu_k = a^{k+1} * mu_in + m_k  (m = zero-init run), p_k = a^{k+1}
// var_out = b^L var_in + Q0 + Q1*mu_in + Q2*mu_in^2   (Q2 host-side)
__global__ __launch_bounds__(256) void k_chunk_summary(
    const float* __restrict__ x, float* __restrict__ ws) {
    const int c = blockIdx.x;
    const int j = threadIdx.x;                  // column group [0,256)
    const int n = CHUNK * D_DIM;
    const float a = 1.0f - ETA_MU_F;
    const float b = 1.0f - ETA_VAR_F;

    vf4 s  = {0.0f, 0.0f, 0.0f, 0.0f};
    vf4 s2 = {0.0f, 0.0f, 0.0f, 0.0f};
    vf4 m  = {0.0f, 0.0f, 0.0f, 0.0f};
    vf4 q0 = {0.0f, 0.0f, 0.0f, 0.0f};
    vf4 q1 = {0.0f, 0.0f, 0.0f, 0.0f};
    float p = 1.0f;

    const vf4* xp = (const vf4*)(x + (size_t)c * CLEN * D_DIM) + j;
#pragma unroll 8
    for (int k = 0; k < CLEN; ++k) {
        vf4 xv = xp[(size_t)k * (D_DIM / 4)];
        p *= a;                                  // p = a^{k+1}
        s  += xv;
        s2 += xv * xv;
        m  += ETA_MU_F * (xv - m);               // same arithmetic form as replay
        vf4 dv = xv - m;
        q0 = b * q0 + ETA_VAR_F * (dv * dv);
        q1 = b * q1 - (2.0f * ETA_VAR_F * p) * dv;
    }
    const int base = c * D_DIM + 4 * j;
    *(vf4*)(ws + 0 * n + base) = s;
    *(vf4*)(ws + 1 * n + base) = s2;
    *(vf4*)(ws + 2 * n + base) = m;
    *(vf4*)(ws + 3 * n + base) = q0;
    *(vf4*)(ws + 4 * n + base) = q1;
}

// K2: per-column. Reduce partials -> mu0, std0 (reference stores STD in the
// var slot initially), then scan the C chunk summaries to get entry states.
// Separate __restrict__ array params: lets the compiler prove the scan's
// loads don't alias the mu_in/var_in stores -> deep software pipelining.
__global__ __launch_bounds__(64) void k_scan(
    const float* __restrict__ sum, const float* __restrict__ sum2,
    const float* __restrict__ bmu, const float* __restrict__ q0,
    const float* __restrict__ q1,
    float* __restrict__ mu_in, float* __restrict__ var_in,
    float a_pow, float b_pow, float q2c) {
    const int d = blockIdx.x * 64 + threadIdx.x;   // [0, D)

    float s = 0.0f, s2 = 0.0f;
#pragma unroll 16
    for (int c = 0; c < CHUNK; ++c) {
        s  += sum[c * D_DIM + d];
        s2 += sum2[c * D_DIM + d];
    }
    float mu0 = s / (float)T_DIM;
    float v0  = (s2 - (float)T_DIM * mu0 * mu0) / (float)(T_DIM - 1);
    float std0 = sqrtf(fmaxf(v0, 0.0f));

    float mu = mu0;
    float var = std0;   // NOTE: std, not variance — matches reference
#pragma unroll 16
    for (int c = 0; c < CHUNK; ++c) {
        int idx = c * D_DIM + d;
        mu_in[idx]  = mu;
        var_in[idx] = var;
        float mu_next = a_pow * mu + bmu[idx];
        var = b_pow * var + q0[idx] + mu * (q1[idx] + q2c * mu);
        mu = mu_next;
    }
}

// K3: replay each chunk with exact reference arithmetic, write outputs.
__global__ __launch_bounds__(256) void k_replay(
    const float* __restrict__ x, const float* __restrict__ ws,
    float* __restrict__ out) {
    const int c = blockIdx.x;
    const int j = threadIdx.x;                  // column group [0,256)
    const int n = CHUNK * D_DIM;
    const int base = c * D_DIM + 4 * j;

    vf4 mu  = *(const vf4*)(ws + 5 * n + base);
    vf4 var = *(const vf4*)(ws + 6 * n + base);

    const size_t t0 = (size_t)c * CLEN;
    const vf4* xp = (const vf4*)(x + t0 * D_DIM) + j;
    vf4* norm_out = (vf4*)(out + t0 * D_DIM) + j;
    float* info_base = out + (size_t)T_DIM * D_DIM + t0 * (2 * D_DIM);
    vf4* mu_out  = (vf4*)(info_base) + j;
    vf4* var_out = (vf4*)(info_base + D_DIM) + j;

#pragma unroll 4
    for (int k = 0; k < CLEN; ++k) {
        vf4 xv = xp[(size_t)k * (D_DIM / 4)];
        mu += ETA_MU_F * (xv - mu);
        vf4 diff = xv - mu;
        var = (1.0f - ETA_VAR_F) * var + ETA_VAR_F * (diff * diff);
        vf4 nrm;
        nrm.x = diff.x / sqrtf(var.x);
        nrm.y = diff.y / sqrtf(var.y);
        nrm.z = diff.z / sqrtf(var.z);
        nrm.w = diff.w / sqrtf(var.w);
        norm_out[(size_t)k * (D_DIM / 4)] = nrm;
        mu_out [(size_t)k * (2 * D_DIM / 4)] = mu;
        var_out[(size_t)k * (2 * D_DIM / 4)] = var;
    }
}

extern "C" void kernel_launch(void* const* d_in, const int* in_sizes, int n_in,
                              void* d_out, int out_size, void* d_ws, size_t ws_size,
                              hipStream_t stream) {
    const float* x = (const float*)d_in[0];
    float* out = (float*)d_out;
    float* ws = (float*)d_ws;

    // Constant decay-over-chunk factors, computed in double on host.
    float a_pow = (float)pow(1.0 - 0.01, (double)CLEN);  // 0.99^64
    float b_pow = (float)pow(1.0 - 0.02, (double)CLEN);  // 0.98^64

    // Q2 = sum_{k=0}^{L-1} b^{L-1-k} * eta_var * a^{2(k+1)}  (data-independent)
    double q2d = 0.0;
    for (int k = 0; k < CLEN; ++k) {
        double pk = pow(0.99, (double)(k + 1));
        q2d = 0.98 * q2d + 0.02 * pk * pk;
    }
    float q2c = (float)q2d;

    const int n = CHUNK * D_DIM;
    hipLaunchKernelGGL(k_chunk_summary, dim3(CHUNK), dim3(256), 0, stream, x, ws);
    hipLaunchKernelGGL(k_scan, dim3(D_DIM / 64), dim3(64), 0, stream,
                       ws + 0 * n, ws + 1 * n, ws + 2 * n, ws + 3 * n, ws + 4 * n,
                       ws + 5 * n, ws + 6 * n, a_pow, b_pow, q2c);
    hipLaunchKernelGGL(k_replay, dim3(CHUNK), dim3(256), 0, stream, x, ws, out);
}

// Round 3
// 586.742 us; speedup vs baseline: 1.1592x; 1.1592x over previous
//
#include <hip/hip_runtime.h>
#include <math.h>

// GASLayer: per-column EMA normalization with chunked parallel scan.
// T=32768 rows, D=1024 cols. C=128 chunks of L=256 rows.
// ANCHOR STRUCTURE (577 us): scalar accesses, 512-block grids, CHUNK=128.
// Deltas vs anchor: (1) K2 takes separate __restrict__ pointers;
//                   (2) q2 is a host-computed double-precision constant
//                       (data-independent), removing one ws array.
// ws layout (floats, n = C*D = 131072 each):
//   [0] sum, [1] sumsq, [2] B_mu, [3] Q0, [4] Q1, [5] mu_in, [6] var_in
// Total ws use: 7 * 131072 * 4 B = 3.5 MiB.

#define T_DIM 32768
#define D_DIM 1024
#define CHUNK 128
#define CLEN  (T_DIM / CHUNK)   // 256
#define ETA_MU_F 0.01f
#define ETA_VAR_F 0.02f

// K1: per-(chunk, column) summaries. One thread per (c,d).
// mu_k = a^{k+1} * mu_in + m_k  (m = zero-init run), p_k = a^{k+1}
// var_out = b^L var_in + Q0 + Q1*mu_in + Q2*mu_in^2   (Q2 host-side)
__global__ __launch_bounds__(256) void k_chunk_summary(
    const float* __restrict__ x, float* __restrict__ ws) {
    const int g = blockIdx.x * 256 + threadIdx.x;   // [0, C*D)
    const int d = g & (D_DIM - 1);
    const int c = g >> 10;
    const float a = 1.0f - ETA_MU_F;
    const float b = 1.0f - ETA_VAR_F;

    float s = 0.0f, s2 = 0.0f;
    float m = 0.0f;                 // mu with mu_in = 0
    float q0 = 0.0f, q1 = 0.0f;
    float p = 1.0f;                 // becomes a^{k+1} after update below

    const float* xp = x + (size_t)c * CLEN * D_DIM + d;
#pragma unroll 4
    for (int k = 0; k < CLEN; ++k) {
        float xv = xp[(size_t)k * D_DIM];
        s  += xv;
        s2 += xv * xv;
        m = m + ETA_MU_F * (xv - m);     // same arithmetic form as replay
        p *= a;                           // p = a^{k+1}
        float dv = xv - m;
        q0 = b * q0 + ETA_VAR_F * dv * dv;
        q1 = b * q1 - 2.0f * ETA_VAR_F * dv * p;
    }
    const int n = CHUNK * D_DIM;
    ws[0 * n + g] = s;
    ws[1 * n + g] = s2;
    ws[2 * n + g] = m;
    ws[3 * n + g] = q0;
    ws[4 * n + g] = q1;
}

// K2: per-column. Reduce partials -> mu0, std0 (reference stores STD in the
// var slot initially), then scan the C chunk summaries to get entry states.
// Separate __restrict__ params so the scan's loads provably don't alias the
// mu_in/var_in stores. Geometry identical to anchor: 4 blocks x 256.
__global__ __launch_bounds__(256) void k_scan(
    const float* __restrict__ sum, const float* __restrict__ sum2,
    const float* __restrict__ bmu, const float* __restrict__ q0,
    const float* __restrict__ q1,
    float* __restrict__ mu_in, float* __restrict__ var_in,
    float a_pow, float b_pow, float q2c) {
    const int d = blockIdx.x * 256 + threadIdx.x;   // [0, D)

    float s = 0.0f, s2 = 0.0f;
#pragma unroll 8
    for (int c = 0; c < CHUNK; ++c) {
        s  += sum[c * D_DIM + d];
        s2 += sum2[c * D_DIM + d];
    }
    float mu0 = s / (float)T_DIM;
    float v0  = (s2 - (float)T_DIM * mu0 * mu0) / (float)(T_DIM - 1);
    float std0 = sqrtf(fmaxf(v0, 0.0f));

    float mu = mu0;
    float var = std0;   // NOTE: std, not variance — matches reference
#pragma unroll 4
    for (int c = 0; c < CHUNK; ++c) {
        int idx = c * D_DIM + d;
        mu_in[idx]  = mu;
        var_in[idx] = var;
        float mu_next = a_pow * mu + bmu[idx];
        var = b_pow * var + q0[idx] + mu * (q1[idx] + q2c * mu);
        mu = mu_next;
    }
}

// K3: replay each chunk with exact reference arithmetic, write outputs.
__global__ __launch_bounds__(256) void k_replay(
    const float* __restrict__ x, const float* __restrict__ ws,
    float* __restrict__ out) {
    const int g = blockIdx.x * 256 + threadIdx.x;   // [0, C*D)
    const int d = g & (D_DIM - 1);
    const int c = g >> 10;
    const int n = CHUNK * D_DIM;

    float mu  = ws[5 * n + g];
    float var = ws[6 * n + g];

    const size_t t0 = (size_t)c * CLEN;
    const float* xp = x + t0 * D_DIM + d;
    float* norm_out = out + t0 * D_DIM + d;
    float* info = out + (size_t)T_DIM * D_DIM + t0 * (2 * D_DIM) + d;

#pragma unroll 4
    for (int k = 0; k < CLEN; ++k) {
        float xv = xp[(size_t)k * D_DIM];
        mu = mu + ETA_MU_F * (xv - mu);
        float diff = xv - mu;
        var = (1.0f - ETA_VAR_F) * var + ETA_VAR_F * diff * diff;
        norm_out[(size_t)k * D_DIM] = diff / sqrtf(var);
        info[(size_t)k * (2 * D_DIM)]         = mu;
        info[(size_t)k * (2 * D_DIM) + D_DIM] = var;
    }
}

extern "C" void kernel_launch(void* const* d_in, const int* in_sizes, int n_in,
                              void* d_out, int out_size, void* d_ws, size_t ws_size,
                              hipStream_t stream) {
    const float* x = (const float*)d_in[0];
    float* out = (float*)d_out;
    float* ws = (float*)d_ws;

    // Constant decay-over-chunk factors, computed in double on host.
    float a_pow = (float)pow(1.0 - 0.01, (double)CLEN);  // 0.99^256
    float b_pow = (float)pow(1.0 - 0.02, (double)CLEN);  // 0.98^256

    // Q2 = sum_{k=0}^{L-1} b^{L-1-k} * eta_var * a^{2(k+1)}  (data-independent)
    double q2d = 0.0;
    for (int k = 0; k < CLEN; ++k) {
        double pk = pow(0.99, (double)(k + 1));
        q2d = 0.98 * q2d + 0.02 * pk * pk;
    }
    float q2c = (float)q2d;

    const int n = CHUNK * D_DIM;               // 131072 threads for K1/K3
    hipLaunchKernelGGL(k_chunk_summary, dim3(n / 256), dim3(256), 0, stream, x, ws);
    hipLaunchKernelGGL(k_scan, dim3(D_DIM / 256), dim3(256), 0, stream,
                       ws + 0 * n, ws + 1 * n, ws + 2 * n, ws + 3 * n, ws + 4 * n,
                       ws + 5 * n, ws + 6 * n, a_pow, b_pow, q2c);
    hipLaunchKernelGGL(k_replay, dim3(n / 256), dim3(256), 0, stream, x, ws, out);
}

// Round 4
// 568.475 us; speedup vs baseline: 1.1964x; 1.0321x over previous
//
#include <hip/hip_runtime.h>
#include <math.h>

// GASLayer: per-column EMA normalization with chunked parallel scan.
// T=32768 rows, D=1024 cols. C=128 chunks of L=256 rows.
// ANCHOR STRUCTURE (577-587 us): scalar accesses, 512-block grids, CHUNK=128.
// Round-4 delta (single lever): K1/K3 row loops unroll 4 -> 16.
//   Rationale: unroll-4 caps in-flight bytes at ~2 MB chip-wide (4 x 256 B
//   per wave x 2048 waves) vs ~5.7 MB needed to cover ~900 ns HBM latency
//   at 6.3 TB/s (Little's law) -> x-reads were latency-bound at ~2.2 TB/s.
// ws layout (floats, n = C*D = 131072 each):
//   [0] sum, [1] sumsq, [2] B_mu, [3] Q0, [4] Q1, [5] mu_in, [6] var_in
// Total ws use: 7 * 131072 * 4 B = 3.5 MiB.

#define T_DIM 32768
#define D_DIM 1024
#define CHUNK 128
#define CLEN  (T_DIM / CHUNK)   // 256
#define ETA_MU_F 0.01f
#define ETA_VAR_F 0.02f

// K1: per-(chunk, column) summaries. One thread per (c,d).
// mu_k = a^{k+1} * mu_in + m_k  (m = zero-init run), p_k = a^{k+1}
// var_out = b^L var_in + Q0 + Q1*mu_in + Q2*mu_in^2   (Q2 host-side)
__global__ __launch_bounds__(256) void k_chunk_summary(
    const float* __restrict__ x, float* __restrict__ ws) {
    const int g = blockIdx.x * 256 + threadIdx.x;   // [0, C*D)
    const int d = g & (D_DIM - 1);
    const int c = g >> 10;
    const float a = 1.0f - ETA_MU_F;
    const float b = 1.0f - ETA_VAR_F;

    float s = 0.0f, s2 = 0.0f;
    float m = 0.0f;                 // mu with mu_in = 0
    float q0 = 0.0f, q1 = 0.0f;
    float p = 1.0f;                 // becomes a^{k+1} after update below

    const float* xp = x + (size_t)c * CLEN * D_DIM + d;
#pragma unroll 16
    for (int k = 0; k < CLEN; ++k) {
        float xv = xp[(size_t)k * D_DIM];
        s  += xv;
        s2 += xv * xv;
        m = m + ETA_MU_F * (xv - m);     // same arithmetic form as replay
        p *= a;                           // p = a^{k+1}
        float dv = xv - m;
        q0 = b * q0 + ETA_VAR_F * dv * dv;
        q1 = b * q1 - 2.0f * ETA_VAR_F * dv * p;
    }
    const int n = CHUNK * D_DIM;
    ws[0 * n + g] = s;
    ws[1 * n + g] = s2;
    ws[2 * n + g] = m;
    ws[3 * n + g] = q0;
    ws[4 * n + g] = q1;
}

// K2: per-column. Reduce partials -> mu0, std0 (reference stores STD in the
// var slot initially), then scan the C chunk summaries to get entry states.
// Separate __restrict__ params so the scan's loads provably don't alias the
// mu_in/var_in stores. Geometry identical to anchor: 4 blocks x 256.
__global__ __launch_bounds__(256) void k_scan(
    const float* __restrict__ sum, const float* __restrict__ sum2,
    const float* __restrict__ bmu, const float* __restrict__ q0,
    const float* __restrict__ q1,
    float* __restrict__ mu_in, float* __restrict__ var_in,
    float a_pow, float b_pow, float q2c) {
    const int d = blockIdx.x * 256 + threadIdx.x;   // [0, D)

    float s = 0.0f, s2 = 0.0f;
#pragma unroll 8
    for (int c = 0; c < CHUNK; ++c) {
        s  += sum[c * D_DIM + d];
        s2 += sum2[c * D_DIM + d];
    }
    float mu0 = s / (float)T_DIM;
    float v0  = (s2 - (float)T_DIM * mu0 * mu0) / (float)(T_DIM - 1);
    float std0 = sqrtf(fmaxf(v0, 0.0f));

    float mu = mu0;
    float var = std0;   // NOTE: std, not variance — matches reference
#pragma unroll 4
    for (int c = 0; c < CHUNK; ++c) {
        int idx = c * D_DIM + d;
        mu_in[idx]  = mu;
        var_in[idx] = var;
        float mu_next = a_pow * mu + bmu[idx];
        var = b_pow * var + q0[idx] + mu * (q1[idx] + q2c * mu);
        mu = mu_next;
    }
}

// K3: replay each chunk with exact reference arithmetic, write outputs.
__global__ __launch_bounds__(256) void k_replay(
    const float* __restrict__ x, const float* __restrict__ ws,
    float* __restrict__ out) {
    const int g = blockIdx.x * 256 + threadIdx.x;   // [0, C*D)
    const int d = g & (D_DIM - 1);
    const int c = g >> 10;
    const int n = CHUNK * D_DIM;

    float mu  = ws[5 * n + g];
    float var = ws[6 * n + g];

    const size_t t0 = (size_t)c * CLEN;
    const float* xp = x + t0 * D_DIM + d;
    float* norm_out = out + t0 * D_DIM + d;
    float* info = out + (size_t)T_DIM * D_DIM + t0 * (2 * D_DIM) + d;

#pragma unroll 16
    for (int k = 0; k < CLEN; ++k) {
        float xv = xp[(size_t)k * D_DIM];
        mu = mu + ETA_MU_F * (xv - mu);
        float diff = xv - mu;
        var = (1.0f - ETA_VAR_F) * var + ETA_VAR_F * diff * diff;
        norm_out[(size_t)k * D_DIM] = diff / sqrtf(var);
        info[(size_t)k * (2 * D_DIM)]         = mu;
        info[(size_t)k * (2 * D_DIM) + D_DIM] = var;
    }
}

extern "C" void kernel_launch(void* const* d_in, const int* in_sizes, int n_in,
                              void* d_out, int out_size, void* d_ws, size_t ws_size,
                              hipStream_t stream) {
    const float* x = (const float*)d_in[0];
    float* out = (float*)d_out;
    float* ws = (float*)d_ws;

    // Constant decay-over-chunk factors, computed in double on host.
    float a_pow = (float)pow(1.0 - 0.01, (double)CLEN);  // 0.99^256
    float b_pow = (float)pow(1.0 - 0.02, (double)CLEN);  // 0.98^256

    // Q2 = sum_{k=0}^{L-1} b^{L-1-k} * eta_var * a^{2(k+1)}  (data-independent)
    double q2d = 0.0;
    for (int k = 0; k < CLEN; ++k) {
        double pk = pow(0.99, (double)(k + 1));
        q2d = 0.98 * q2d + 0.02 * pk * pk;
    }
    float q2c = (float)q2d;

    const int n = CHUNK * D_DIM;               // 131072 threads for K1/K3
    hipLaunchKernelGGL(k_chunk_summary, dim3(n / 256), dim3(256), 0, stream, x, ws);
    hipLaunchKernelGGL(k_scan, dim3(D_DIM / 256), dim3(256), 0, stream,
                       ws + 0 * n, ws + 1 * n, ws + 2 * n, ws + 3 * n, ws + 4 * n,
                       ws + 5 * n, ws + 6 * n, a_pow, b_pow, q2c);
    hipLaunchKernelGGL(k_replay, dim3(n / 256), dim3(256), 0, stream, x, ws, out);
}

// Round 6
// 559.150 us; speedup vs baseline: 1.2164x; 1.0167x over previous
//
#include <hip/hip_runtime.h>
#include <math.h>

// GASLayer: per-column EMA normalization with chunked parallel scan.
// T=32768 rows, D=1024 cols. C=128 chunks of L=256 rows.
// ANCHOR STRUCTURE (568 us, round 4): scalar accesses, 512-block grids,
// CHUNK=128, K1/K3 row loops unroll 16.
// Round-6 = round-5 resubmit after infra failure, with rsqrtf() replacing
// __builtin_amdgcn_rsqf (same v_rsq_f32, portable spelling):
//   (1) K2 unroll 4/8 -> 16 on both loops: its 16 waves read chunk
//       summaries from remote XCD L2s (~700 cyc); unroll-4 exposed that
//       latency every ~12 loads. 16x unroll -> ~48 affine loads in
//       flight per body.
//   (2) K3 uses diff * rsqrtf(var) instead of the precise div+sqrt
//       sequence (~15 VALU instrs -> 2 per element).
//       var ~ O(1): rel err ~1e-6, invisible vs passing absmax 1.6e-2.
// ws layout (floats, n = C*D = 131072 each):
//   [0] sum, [1] sumsq, [2] B_mu, [3] Q0, [4] Q1, [5] mu_in, [6] var_in

#define T_DIM 32768
#define D_DIM 1024
#define CHUNK 128
#define CLEN  (T_DIM / CHUNK)   // 256
#define ETA_MU_F 0.01f
#define ETA_VAR_F 0.02f

// K1: per-(chunk, column) summaries. One thread per (c,d).
// mu_k = a^{k+1} * mu_in + m_k  (m = zero-init run), p_k = a^{k+1}
// var_out = b^L var_in + Q0 + Q1*mu_in + Q2*mu_in^2   (Q2 host-side)
__global__ __launch_bounds__(256) void k_chunk_summary(
    const float* __restrict__ x, float* __restrict__ ws) {
    const int g = blockIdx.x * 256 + threadIdx.x;   // [0, C*D)
    const int d = g & (D_DIM - 1);
    const int c = g >> 10;
    const float a = 1.0f - ETA_MU_F;
    const float b = 1.0f - ETA_VAR_F;

    float s = 0.0f, s2 = 0.0f;
    float m = 0.0f;                 // mu with mu_in = 0
    float q0 = 0.0f, q1 = 0.0f;
    float p = 1.0f;                 // becomes a^{k+1} after update below

    const float* xp = x + (size_t)c * CLEN * D_DIM + d;
#pragma unroll 16
    for (int k = 0; k < CLEN; ++k) {
        float xv = xp[(size_t)k * D_DIM];
        s  += xv;
        s2 += xv * xv;
        m = m + ETA_MU_F * (xv - m);     // same arithmetic form as replay
        p *= a;                           // p = a^{k+1}
        float dv = xv - m;
        q0 = b * q0 + ETA_VAR_F * dv * dv;
        q1 = b * q1 - 2.0f * ETA_VAR_F * dv * p;
    }
    const int n = CHUNK * D_DIM;
    ws[0 * n + g] = s;
    ws[1 * n + g] = s2;
    ws[2 * n + g] = m;
    ws[3 * n + g] = q0;
    ws[4 * n + g] = q1;
}

// K2: per-column. Reduce partials -> mu0, std0 (reference stores STD in the
// var slot initially), then scan the C chunk summaries to get entry states.
// Separate __restrict__ params + unroll 16 so each unrolled body issues
// ~48 independent loads before any consume -> cross-XCD L2 latency
// (~700 cyc) is exposed ~8x per column instead of ~32x.
__global__ __launch_bounds__(256) void k_scan(
    const float* __restrict__ sum, const float* __restrict__ sum2,
    const float* __restrict__ bmu, const float* __restrict__ q0,
    const float* __restrict__ q1,
    float* __restrict__ mu_in, float* __restrict__ var_in,
    float a_pow, float b_pow, float q2c) {
    const int d = blockIdx.x * 256 + threadIdx.x;   // [0, D)

    float s = 0.0f, s2 = 0.0f;
#pragma unroll 16
    for (int c = 0; c < CHUNK; ++c) {
        s  += sum[c * D_DIM + d];
        s2 += sum2[c * D_DIM + d];
    }
    float mu0 = s / (float)T_DIM;
    float v0  = (s2 - (float)T_DIM * mu0 * mu0) / (float)(T_DIM - 1);
    float std0 = sqrtf(fmaxf(v0, 0.0f));

    float mu = mu0;
    float var = std0;   // NOTE: std, not variance — matches reference
#pragma unroll 16
    for (int c = 0; c < CHUNK; ++c) {
        int idx = c * D_DIM + d;
        mu_in[idx]  = mu;
        var_in[idx] = var;
        float mu_next = a_pow * mu + bmu[idx];
        var = b_pow * var + q0[idx] + mu * (q1[idx] + q2c * mu);
        mu = mu_next;
    }
}

// K3: replay each chunk with exact reference arithmetic, write outputs.
// norm = diff * rsqrtf(var): v_rsq_f32 + v_mul (2 VALU instrs) vs ~15 for
// the precise div+sqrt sequence.
__global__ __launch_bounds__(256) void k_replay(
    const float* __restrict__ x, const float* __restrict__ ws,
    float* __restrict__ out) {
    const int g = blockIdx.x * 256 + threadIdx.x;   // [0, C*D)
    const int d = g & (D_DIM - 1);
    const int c = g >> 10;
    const int n = CHUNK * D_DIM;

    float mu  = ws[5 * n + g];
    float var = ws[6 * n + g];

    const size_t t0 = (size_t)c * CLEN;
    const float* xp = x + t0 * D_DIM + d;
    float* norm_out = out + t0 * D_DIM + d;
    float* info = out + (size_t)T_DIM * D_DIM + t0 * (2 * D_DIM) + d;

#pragma unroll 16
    for (int k = 0; k < CLEN; ++k) {
        float xv = xp[(size_t)k * D_DIM];
        mu = mu + ETA_MU_F * (xv - mu);
        float diff = xv - mu;
        var = (1.0f - ETA_VAR_F) * var + ETA_VAR_F * diff * diff;
        norm_out[(size_t)k * D_DIM] = diff * rsqrtf(var);
        info[(size_t)k * (2 * D_DIM)]         = mu;
        info[(size_t)k * (2 * D_DIM) + D_DIM] = var;
    }
}

extern "C" void kernel_launch(void* const* d_in, const int* in_sizes, int n_in,
                              void* d_out, int out_size, void* d_ws, size_t ws_size,
                              hipStream_t stream) {
    const float* x = (const float*)d_in[0];
    float* out = (float*)d_out;
    float* ws = (float*)d_ws;

    // Constant decay-over-chunk factors, computed in double on host.
    float a_pow = (float)pow(1.0 - 0.01, (double)CLEN);  // 0.99^256
    float b_pow = (float)pow(1.0 - 0.02, (double)CLEN);  // 0.98^256

    // Q2 = sum_{k=0}^{L-1} b^{L-1-k} * eta_var * a^{2(k+1)}  (data-independent)
    double q2d = 0.0;
    for (int k = 0; k < CLEN; ++k) {
        double pk = pow(0.99, (double)(k + 1));
        q2d = 0.98 * q2d + 0.02 * pk * pk;
    }
    float q2c = (float)q2d;

    const int n = CHUNK * D_DIM;               // 131072 threads for K1/K3
    hipLaunchKernelGGL(k_chunk_summary, dim3(n / 256), dim3(256), 0, stream, x, ws);
    hipLaunchKernelGGL(k_scan, dim3(D_DIM / 256), dim3(256), 0, stream,
                       ws + 0 * n, ws + 1 * n, ws + 2 * n, ws + 3 * n, ws + 4 * n,
                       ws + 5 * n, ws + 6 * n, a_pow, b_pow, q2c);
    hipLaunchKernelGGL(k_replay, dim3(n / 256), dim3(256), 0, stream, x, ws, out);
}